// Round 7
// baseline (262.897 us; speedup 1.0000x reference)
//
#include <hip/hip_runtime.h>

#define NROWS 4096
#define NDOM 8

typedef short short8 __attribute__((ext_vector_type(8)));
typedef float floatx4 __attribute__((ext_vector_type(4)));
typedef unsigned short ushort8v __attribute__((ext_vector_type(8)));

__device__ __forceinline__ unsigned short f2bf(float f) {
    union { float f; unsigned u; } v; v.f = f;
    unsigned r = v.u + 0x7FFFu + ((v.u >> 16) & 1u);  // RNE
    return (unsigned short)(r >> 16);
}

// ---------------------------------------------------------------------------
// Fused precompute dispatch (unchanged from R6 — it works):
//   blocks [0,256)     : xb = bf16(x), original row order
//   blocks [256,768)   : w0t = bf16(sk0*dk0) transposed [d][n][k]
//   blocks [768,1024)  : w1t
//   blocks [1024,1088) : w2t
//   block 1088         : deterministic counting-sort -> offsets, rowidx
// ---------------------------------------------------------------------------

template <int K, int N>
__device__ __forceinline__ void weff_tile(const float* __restrict__ sk,
                                          const float* __restrict__ dk,
                                          unsigned short* __restrict__ wt,
                                          unsigned short* __restrict__ lds,
                                          int local) {
    const int d = local & 7;
    const int rest = local >> 3;
    const int k0 = (rest & (K / 256 - 1)) * 256;
    const int n0 = (rest / (K / 256)) * 64;
    const int t = threadIdx.x;

    const int n = t & 63;
    const int kg = (t >> 6) * 64;
#pragma unroll
    for (int c8 = 0; c8 < 8; ++c8) {
        const int kb = k0 + kg + c8 * 8;
        unsigned short wb[8];
#pragma unroll
        for (int i = 0; i < 8; ++i) {
            int k = kb + i;
            wb[i] = f2bf(sk[(size_t)k * N + n0 + n] * dk[((size_t)d * K + k) * N + n0 + n]);
        }
        int ch = (kg + c8 * 8) >> 3;
        int phys = ch ^ (n & 31);
        *(ushort8v*)&lds[n * 256 + phys * 8] = *(ushort8v*)wb;
    }
    __syncthreads();

#pragma unroll
    for (int it = 0; it < 4; ++it) {
        const int nn = (t >> 4) + it * 16;
        const int c = t & 15;
        ushort8v a = *(ushort8v*)&lds[nn * 256 + ((2 * c) ^ (nn & 31)) * 8];
        ushort8v b = *(ushort8v*)&lds[nn * 256 + ((2 * c + 1) ^ (nn & 31)) * 8];
        unsigned short* dst = wt + ((size_t)d * N + n0 + nn) * K + k0 + c * 16;
        *(ushort8v*)dst = a;
        *(ushort8v*)(dst + 8) = b;
    }
}

__global__ void precompute_kernel(const float* __restrict__ x,
                                  const int* __restrict__ ind,
                                  const float* __restrict__ sk0, const float* __restrict__ dk0,
                                  const float* __restrict__ sk1, const float* __restrict__ dk1,
                                  const float* __restrict__ sk2, const float* __restrict__ dk2,
                                  unsigned short* __restrict__ xb,
                                  unsigned short* __restrict__ w0t,
                                  unsigned short* __restrict__ w1t,
                                  unsigned short* __restrict__ w2t,
                                  int* __restrict__ offsets,
                                  int* __restrict__ rowidx) {
    __shared__ unsigned short wtile[64 * 256];
    __shared__ unsigned short cnt[256][NDOM];
    __shared__ int base[256][NDOM];
    __shared__ int dom_total[NDOM];
    __shared__ int dom_off[NDOM + 1];

    const int b = blockIdx.x;
    const int t = threadIdx.x;

    if (b < 256) {
#pragma unroll
        for (int pass = 0; pass < 8; ++pass) {
            int row = b * 16 + pass * 2 + (t >> 7);
            int ch = t & 127;
            const float* src = x + (size_t)row * 1024 + ch * 8;
            floatx4 v0 = *(const floatx4*)src;
            floatx4 v1 = *(const floatx4*)(src + 4);
            unsigned short o[8];
            o[0] = f2bf(v0[0]); o[1] = f2bf(v0[1]); o[2] = f2bf(v0[2]); o[3] = f2bf(v0[3]);
            o[4] = f2bf(v1[0]); o[5] = f2bf(v1[1]); o[6] = f2bf(v1[2]); o[7] = f2bf(v1[3]);
            *(ushort8v*)(xb + (size_t)row * 1024 + ch * 8) = *(ushort8v*)o;
        }
    } else if (b < 256 + 512) {
        weff_tile<1024, 1024>(sk0, dk0, w0t, wtile, b - 256);
    } else if (b < 256 + 512 + 256) {
        weff_tile<1024, 512>(sk1, dk1, w1t, wtile, b - (256 + 512));
    } else if (b < 256 + 512 + 256 + 64) {
        weff_tile<512, 256>(sk2, dk2, w2t, wtile, b - (256 + 512 + 256));
    } else {
        int myind[16];
#pragma unroll
        for (int i = 0; i < 16; ++i) myind[i] = ind[t * 16 + i];
        unsigned short c[NDOM];
#pragma unroll
        for (int d = 0; d < NDOM; ++d) c[d] = 0;
#pragma unroll
        for (int i = 0; i < 16; ++i) c[myind[i]]++;
#pragma unroll
        for (int d = 0; d < NDOM; ++d) cnt[t][d] = c[d];
        __syncthreads();
        if (t < NDOM) {
            int acc = 0;
            for (int ch = 0; ch < 256; ++ch) { base[ch][t] = acc; acc += cnt[ch][t]; }
            dom_total[t] = acc;
        }
        __syncthreads();
        if (t == 0) {
            int acc = 0;
            for (int d = 0; d < NDOM; ++d) { dom_off[d] = acc; acc += dom_total[d]; }
            dom_off[NDOM] = acc;
        }
        __syncthreads();
        int pos[NDOM];
#pragma unroll
        for (int d = 0; d < NDOM; ++d) pos[d] = dom_off[d] + base[t][d];
#pragma unroll
        for (int i = 0; i < 16; ++i) {
            int dm = myind[i];
            rowidx[pos[dm]++] = t * 16 + i;
        }
        if (t <= NDOM) offsets[t] = dom_off[t];
    }
}

// ---------------------------------------------------------------------------
// Grouped GEMM, direct-to-register: NO LDS, NO barriers. Each wave owns an
// independent (FM*16)x(FN*16) tile. Both Ab[row][k] and Wt[n][k] are already
// in MFMA operand layout: frag load = per-lane global_load_dwordx4 at
// (row = lane&15, k = quad*8 + s*32). Triple-buffered k-pipeline: frag loads
// for step s+3 issue after compute(s) -> ~2 MFMA-phases of latency cover,
// waits are compiler fine-grained vmcnt (no vmcnt(0) barrier drain anywhere).
// ---------------------------------------------------------------------------
template <int FM, int FN, int MSLOTS, int K, int N, bool GATHER, bool SCATTER>
__launch_bounds__(256, 1)
__global__ void star_gemm(const unsigned short* __restrict__ Ab,
                          const unsigned short* __restrict__ Wt,
                          const float* __restrict__ sb,
                          const float* __restrict__ db,
                          float* __restrict__ OutF,
                          unsigned short* __restrict__ OutB,
                          const int* __restrict__ offsets,
                          const int* __restrict__ rowidx) {
    constexpr int TM = FM * 16;
    constexpr int TN = FN * 16;
    constexpr int NS = K / 32;                  // 32-wide k steps

    const int gid = blockIdx.x;
    const int w = threadIdx.x >> 6;
    const int lane = threadIdx.x & 63;
    const int lm = lane & 15;
    const int quad = lane >> 4;

    const int d = gid & 7;                      // domain -> XCD round-robin
    const int rest = (gid >> 3) * 4 + w;        // 0..127: independent wave tile
    const int mslot = rest % MSLOTS;
    const int n0 = (rest / MSLOTS) * TN;

    const int bstart = offsets[d];
    const int bend = offsets[d + 1];
    const int bsize = bend - bstart;

    float bias[FN];
    const unsigned short* wp[FN];
#pragma unroll
    for (int j = 0; j < FN; ++j) {
        int n = n0 + j * 16 + lm;
        bias[j] = sb[n] + db[d * N + n];
        wp[j] = Wt + ((size_t)d * N + n) * K + quad * 8;
    }

    for (int mt = mslot; mt * TM < bsize; mt += MSLOTS) {
        const int row_start = bstart + mt * TM;

        const unsigned short* ap[FM];
#pragma unroll
        for (int i = 0; i < FM; ++i) {
            int p = row_start + i * 16 + lm;
            if (p >= bend) p = bend - 1;        // in-bucket clamp
            int src = GATHER ? rowidx[p] : p;
            ap[i] = Ab + (size_t)src * K + quad * 8;
        }

        floatx4 acc[FM][FN];
#pragma unroll
        for (int i = 0; i < FM; ++i)
#pragma unroll
            for (int j = 0; j < FN; ++j) acc[i][j] = floatx4{0.f, 0.f, 0.f, 0.f};

        short8 ab[3][FM], wb[3][FN];
        auto load = [&](int s, int buf) {
#pragma unroll
            for (int i = 0; i < FM; ++i)
                ab[buf][i] = *(const short8*)(ap[i] + s * 32);
#pragma unroll
            for (int j = 0; j < FN; ++j)
                wb[buf][j] = *(const short8*)(wp[j] + s * 32);
        };

        load(0, 0);
        load(1, 1);
        load(2, 2);
#pragma unroll
        for (int s = 0; s < NS; ++s) {
            const int buf = s % 3;
#pragma unroll
            for (int i = 0; i < FM; ++i)
#pragma unroll
                for (int j = 0; j < FN; ++j)
                    acc[i][j] = __builtin_amdgcn_mfma_f32_16x16x32_bf16(
                        ab[buf][i], wb[buf][j], acc[i][j], 0, 0, 0);
            if (s + 3 < NS) load(s + 3, buf);   // refill the buffer just consumed
        }

        // epilogue: bias + relu; C layout col=lane&15, row=quad*4+reg
#pragma unroll
        for (int i = 0; i < FM; ++i) {
#pragma unroll
            for (int rg = 0; rg < 4; ++rg) {
                int m = i * 16 + quad * 4 + rg;
                int p = row_start + m;
                if (p < bend) {
                    if constexpr (SCATTER) {
                        int orow = rowidx[p];
#pragma unroll
                        for (int j = 0; j < FN; ++j) {
                            int n = n0 + j * 16 + lm;
                            float v = acc[i][j][rg] + bias[j];
                            OutF[(size_t)orow * N + n] = v > 0.f ? v : 0.f;
                        }
                    } else {
#pragma unroll
                        for (int j = 0; j < FN; ++j) {
                            int n = n0 + j * 16 + lm;
                            float v = acc[i][j][rg] + bias[j];
                            OutB[(size_t)p * N + n] = f2bf(v > 0.f ? v : 0.f);
                        }
                    }
                }
            }
        }
    }
}

extern "C" void kernel_launch(void* const* d_in, const int* in_sizes, int n_in,
                              void* d_out, int out_size, void* d_ws, size_t ws_size,
                              hipStream_t stream) {
    const float* x = (const float*)d_in[0];
    const int* ind = (const int*)d_in[1];
    const float* sk0 = (const float*)d_in[2];
    const float* sb0 = (const float*)d_in[3];
    const float* dk0 = (const float*)d_in[4];
    const float* db0 = (const float*)d_in[5];
    const float* sk1 = (const float*)d_in[6];
    const float* sb1 = (const float*)d_in[7];
    const float* dk1 = (const float*)d_in[8];
    const float* db1 = (const float*)d_in[9];
    const float* sk2 = (const float*)d_in[10];
    const float* sb2 = (const float*)d_in[11];
    const float* dk2 = (const float*)d_in[12];
    const float* db2 = (const float*)d_in[13];
    float* out = (float*)d_out;

    // workspace layout (~46 MB)
    char* ws = (char*)d_ws;
    int* offsets = (int*)ws;                                      // 64 B
    int* rowidx = (int*)(ws + 256);                               // 16 KB
    unsigned short* xb  = (unsigned short*)(ws + 32768);          // 8 MB  bf16 x, original order
    unsigned short* h1  = xb + (size_t)NROWS * 1024;              // 8 MB  bucket order
    unsigned short* h2  = h1 + (size_t)NROWS * 1024;              // 4 MB  bucket order
    unsigned short* w0t = h2 + (size_t)NROWS * 512;               // 16 MB [d][n=1024][k=1024]
    unsigned short* w1t = w0t + (size_t)NDOM * 1024 * 1024;       // 8 MB  [d][n=512][k=1024]
    unsigned short* w2t = w1t + (size_t)NDOM * 512 * 1024;        // 2 MB  [d][n=256][k=512]

    precompute_kernel<<<256 + 512 + 256 + 64 + 1, 256, 0, stream>>>(
        x, ind, sk0, dk0, sk1, dk1, sk2, dk2, xb, w0t, w1t, w2t, offsets, rowidx);

    // L0: 64x64 wave tiles, 8d x 8m x 16n = 1024 waves = 256 blocks
    star_gemm<4, 4, 8, 1024, 1024, true, false><<<256, 256, 0, stream>>>(
        xb, w0t, sb0, db0, nullptr, h1, offsets, rowidx);
    // L1: 32x64 wave tiles, 8d x 16m x 8n = 1024 waves = 256 blocks
    star_gemm<2, 4, 16, 1024, 512, false, false><<<256, 256, 0, stream>>>(
        h1, w1t, sb1, db1, nullptr, h2, offsets, rowidx);
    // L2: 32x32 wave tiles, 8d x 16m x 8n = 1024 waves = 256 blocks
    star_gemm<2, 2, 16, 512, 256, false, true><<<256, 256, 0, stream>>>(
        h2, w2t, sb2, db2, out, nullptr, offsets, rowidx);
}